// Round 20
// baseline (99.863 us; speedup 1.0000x reference)
//
#include <hip/hip_runtime.h>
#include <hip/hip_bf16.h>

#define B_ 2
#define S_ 2048
#define D_ 1024
#define H_ 16
#define DK_ 64
#define M_ (B_*S_)   // 4096 rows
#define K_ D_        // 1024 reduction dim

typedef __attribute__((ext_vector_type(8))) short bf16x8;
typedef __attribute__((ext_vector_type(4))) float f32x4;

__device__ __forceinline__ unsigned short f2bf(float f) {
  unsigned u = __float_as_uint(f);
  u += 0x7fff + ((u >> 16) & 1);   // round-to-nearest-even
  return (unsigned short)(u >> 16);
}

// async global->LDS, 16B per lane. LDS base wave-uniform; HW writes base+lane*16.
__device__ __forceinline__ void gload_lds16(const void* g, void* l) {
  __builtin_amdgcn_global_load_lds(
      (const __attribute__((address_space(1))) unsigned int*)(unsigned long long)g,
      (__attribute__((address_space(3))) unsigned int*)(unsigned int)(unsigned long long)l,
      16, 0, 0);
}

// ---------------- unified fp32->bf16 convert + RoPE table, one launch ------
__global__ __launch_bounds__(256) void k_cvt(
    const float* __restrict__ x,
    const float* __restrict__ w0, const float* __restrict__ w1,
    const float* __restrict__ w2, const float* __restrict__ w3,
    unsigned short* __restrict__ xb, unsigned short* __restrict__ wb,
    const int* __restrict__ pos, float2* __restrict__ tab) {
  const int bid = blockIdx.x;
  if (bid >= 8192) {
    int t = (bid - 8192) * 256 + threadIdx.x;   // S*32
    int s = t >> 5, j = t & 31;
    float inv = powf(10000.0f, -(float)j / 32.0f);
    float ang = (float)pos[s] * inv;
    tab[t] = make_float2(cosf(ang), sinf(ang));
    return;
  }
  const float* sp;
  unsigned short* dp;
  size_t off;
  if (bid < 4096) {
    sp = x; dp = xb; off = (size_t)bid * 1024 + threadIdx.x * 4;
  } else {
    const int wi = (bid - 4096) >> 10;
    sp = (wi == 0) ? w0 : (wi == 1) ? w1 : (wi == 2) ? w2 : w3;
    dp = wb + (size_t)wi * D_ * K_;
    off = (size_t)((bid - 4096) & 1023) * 1024 + threadIdx.x * 4;
  }
  float4 v = *(const float4*)(sp + off);
  ushort4 o;
  o.x = f2bf(v.x); o.y = f2bf(v.y); o.z = f2bf(v.z); o.w = f2bf(v.w);
  *(ushort4*)(dp + off) = o;
}

// ---------------- QKV GEMM: 128x192 tiles, BK=64, 8 WAVES (unchanged) ------
__global__ __launch_bounds__(512, 4) void k_gemm0(
    const unsigned short* __restrict__ A,      // [M,K] bf16 (x)
    const unsigned short* __restrict__ Wall,   // concat (Wq;Wk;Wv) [3072,1024]
    unsigned short* __restrict__ qkv,          // [z][B*H][...] outputs
    const float2* __restrict__ tab)
{
  __shared__ unsigned short SA[2][128*64];     // 32KB
  __shared__ unsigned short SB[2][192*64];     // 48KB
  const int tid = threadIdx.x, lane = tid & 63, w = tid >> 6;   // w 0..7
  const int wr = w >> 2, wc = w & 3;           // 2x4 wave grid
  const int c = lane & 15, hg = lane >> 4;
  const int m0 = blockIdx.x * 128;
  const int n0 = blockIdx.y * 192;             // in concat col space [0,3072)
  const unsigned short* Ag = A + (size_t)m0 * K_;
  const unsigned short* Bg = Wall + (size_t)n0 * K_;

  f32x4 acc[4][3];
#pragma unroll
  for (int m = 0; m < 4; ++m)
#pragma unroll
    for (int n = 0; n < 3; ++n) acc[m][n] = (f32x4){0.f, 0.f, 0.f, 0.f};

  const int srow   = w*8 + (lane >> 3);        // + i*64 (8 waves x 8 rows/round)
  const int schunk = (lane & 7) ^ (lane >> 3); // source chunk XOR row&7

#define GS0(KT, BI)                                                           \
  do {                                                                        \
    _Pragma("unroll")                                                         \
    for (int i = 0; i < 2; ++i)                                               \
      gload_lds16(Ag + (size_t)(i*64 + srow)*K_ + (KT) + schunk*8,            \
                  &SA[BI][(i*64 + w*8)*64]);                                  \
    _Pragma("unroll")                                                         \
    for (int i = 0; i < 3; ++i)                                               \
      gload_lds16(Bg + (size_t)(i*64 + srow)*K_ + (KT) + schunk*8,            \
                  &SB[BI][(i*64 + w*8)*64]);                                  \
  } while (0)

  GS0(0, 0);
  for (int t = 0; t < K_/64; ++t) {
    asm volatile("s_waitcnt vmcnt(0)" ::: "memory");
    __builtin_amdgcn_s_barrier();
    asm volatile("" ::: "memory");
    if (t + 1 < K_/64) GS0((t+1)*64, (t & 1) ^ 1);

    const int bi = t & 1;
#pragma unroll
    for (int kk = 0; kk < 2; ++kk) {
      bf16x8 af[4], bfr[3];
#pragma unroll
      for (int m = 0; m < 4; ++m)
        af[m] = *(const bf16x8*)&SA[bi][(wr*64 + m*16 + c)*64 + (((kk*4 + hg) ^ (c & 7))*8)];
#pragma unroll
      for (int n = 0; n < 3; ++n)
        bfr[n] = *(const bf16x8*)&SB[bi][(wc*48 + n*16 + c)*64 + (((kk*4 + hg) ^ (c & 7))*8)];
#pragma unroll
      for (int m = 0; m < 4; ++m)
#pragma unroll
        for (int n = 0; n < 3; ++n)
          acc[m][n] = __builtin_amdgcn_mfma_f32_16x16x32_bf16(af[m], bfr[n], acc[m][n], 0, 0, 0);
    }
  }
#undef GS0

#pragma unroll
  for (int m = 0; m < 4; ++m)
#pragma unroll
    for (int n = 0; n < 3; ++n) {
      const int row0 = m0 + wr*64 + m*16 + hg*4;
      const int col  = n0 + wc*48 + n*16 + c;
      const int z = col >> 10;
      const int colz = col & 1023;
      const int h = colz >> 6, d = colz & 63;
      unsigned short* dst = qkv + (size_t)z * M_ * D_;
      if (z == 2) {
        // V^T: [B*H][DK][S], 4 consecutive s per lane (8B store)
        const int b = row0 >> 11, s0 = row0 & (S_ - 1);
        ushort4 o;
        o.x = f2bf(acc[m][n][0]); o.y = f2bf(acc[m][n][1]);
        o.z = f2bf(acc[m][n][2]); o.w = f2bf(acc[m][n][3]);
        *(ushort4*)&dst[((size_t)(b*H_ + h)*DK_ + d)*S_ + s0] = o;
      } else {
        const float post = (z == 0) ? 0.18033688f : 1.0f;   // 0.125*log2(e)
        const float sgn = (d & 1) ? 1.0f : -1.0f;
#pragma unroll
        for (int r = 0; r < 4; ++r) {
          const int row = row0 + r;
          const int b = row >> 11, s = row & (S_ - 1);
          float v  = acc[m][n][r];
          float pv = __shfl_xor(v, 1);          // pair partner: d^1 == lane^1
          float2 cs = tab[s*32 + (d >> 1)];
          float ov = (v * cs.x + sgn * pv * cs.y) * post;
          dst[((size_t)(b*H_ + h)*S_ + s)*DK_ + d] = f2bf(ov);
        }
      }
    }
}

// ---------------- output GEMM: attn @ Wo^T, 64x128 tiles, 8 WAVES ----------
__global__ __launch_bounds__(512, 4) void k_gemm1(
    const unsigned short* __restrict__ A,      // [M,K] bf16 (attn)
    const unsigned short* __restrict__ Wo,     // [D,K] bf16
    float* __restrict__ fout)                  // [M,D] fp32 (d_out)
{
  __shared__ unsigned short As[2][64*64];      // 16KB
  __shared__ unsigned short Bs[2][128*64];     // 32KB
  const int tid = threadIdx.x, lane = tid & 63, w = tid >> 6;   // w 0..7
  const int wr = w >> 2, wc = w & 3;           // 2x4 wave grid; wave-tile 32x32
  const int c = lane & 15, hg = lane >> 4;
  const int m0 = blockIdx.x * 64, n0 = blockIdx.y * 128;
  const unsigned short* Ag = A + (size_t)m0 * K_;
  const unsigned short* Bg = Wo + (size_t)n0 * K_;

  f32x4 acc[2][2];
#pragma unroll
  for (int m = 0; m < 2; ++m)
#pragma unroll
    for (int n = 0; n < 2; ++n) acc[m][n] = (f32x4){0.f, 0.f, 0.f, 0.f};

  const int srow   = w*8 + (lane >> 3);
  const int schunk = (lane & 7) ^ (lane >> 3);

#define GS1(KT, BI)                                                           \
  do {                                                                        \
    gload_lds16(Ag + (size_t)srow*K_ + (KT) + schunk*8,                       \
                &As[BI][(w*8)*64]);                                           \
    _Pragma("unroll")                                                         \
    for (int i = 0; i < 2; ++i)                                               \
      gload_lds16(Bg + (size_t)(i*64 + srow)*K_ + (KT) + schunk*8,            \
                  &Bs[BI][(i*64 + w*8)*64]);                                  \
  } while (0)

  GS1(0, 0);
  for (int t = 0; t < K_/64; ++t) {
    asm volatile("s_waitcnt vmcnt(0)" ::: "memory");
    __builtin_amdgcn_s_barrier();
    asm volatile("" ::: "memory");
    if (t + 1 < K_/64) GS1((t+1)*64, (t & 1) ^ 1);

    const int bi = t & 1;
#pragma unroll
    for (int kk = 0; kk < 2; ++kk) {
      bf16x8 af[2], bfr[2];
#pragma unroll
      for (int m = 0; m < 2; ++m)
        af[m] = *(const bf16x8*)&As[bi][(wr*32 + m*16 + c)*64 + (((kk*4 + hg) ^ (c & 7))*8)];
#pragma unroll
      for (int n = 0; n < 2; ++n)
        bfr[n] = *(const bf16x8*)&Bs[bi][(wc*32 + n*16 + c)*64 + (((kk*4 + hg) ^ (c & 7))*8)];
#pragma unroll
      for (int m = 0; m < 2; ++m)
#pragma unroll
        for (int n = 0; n < 2; ++n)
          acc[m][n] = __builtin_amdgcn_mfma_f32_16x16x32_bf16(af[m], bfr[n], acc[m][n], 0, 0, 0);
    }
  }
#undef GS1

#pragma unroll
  for (int m = 0; m < 2; ++m)
#pragma unroll
    for (int n = 0; n < 2; ++n) {
      const int row0 = m0 + wr*32 + m*16 + hg*4;
      const int col  = n0 + wc*32 + n*16 + c;
#pragma unroll
      for (int r = 0; r < 4; ++r)
        fout[(size_t)(row0 + r)*D_ + col] = acc[m][n][r];
    }
}

// ---------------- causal flash attention: 1024 blocks, 4 blocks/CU ---------
// LDS = 40KB exactly (K/V dbuf 32KB + Ps 8KB XOR-swizzled, stride 64) ->
// 4 blocks/CU resident (exact-fit grid). Static balance: the 4 blocks sharing
// a CU slot (bid +- 256*m under round-robin dispatch) get qt {2k, 31-2k,
// 2k+1, 30-2k} -> per-slot step-sum 62 for every k. bv loads back after QK^T
// (r19 hoist reverted: neutral-negative).
__global__ __launch_bounds__(256) void k_attn(
    const unsigned short* __restrict__ Qg,   // [B*H][S][DK]
    const unsigned short* __restrict__ Kg,   // [B*H][S][DK]
    const unsigned short* __restrict__ Vtg,  // [B*H][DK][S]
    unsigned short* __restrict__ Og)         // [B][S][D]
{
  __shared__ unsigned short Kb[2][64*64];    // 16KB
  __shared__ unsigned short Vb[2][64*64];    // 16KB
  __shared__ unsigned short Ps[4][16*64];    // 8KB, XOR chunk-swizzled

  const int tid = threadIdx.x, lane = tid & 63, w = tid >> 6;
  const int bid = blockIdx.x;                // 0..1023
  const int xcd = bid & 7, sub = (bid >> 3) & 3;
  const int head = xcd * 4 + (sub);          // 4 heads per XCD (KV L2-resident)
  const int j = bid >> 5;                    // 0..31
  const int k = j & 7, mq = j >> 3;
  const int qt = (mq == 0) ? (2*k) : (mq == 1) ? (31 - 2*k)
               : (mq == 2) ? (2*k + 1) : (30 - 2*k);
  const int q0 = qt * 64 + w * 16;           // this wave's first q row
  const int c = lane & 15, hg = lane >> 4;

  const unsigned short* Qp = Qg + (size_t)head * S_ * DK_;
  const unsigned short* Kp = Kg + (size_t)head * S_ * DK_;
  const unsigned short* Vp = Vtg + (size_t)head * DK_ * S_;

  const int srow   = w*8 + (lane >> 3);
  const int schunk = (lane & 7) ^ (lane >> 3);

  const short ONE_BF = (short)0x3F80;
  const bf16x8 vones = {ONE_BF, ONE_BF, ONE_BF, ONE_BF, ONE_BF, ONE_BF, ONE_BF, ONE_BF};
  const f32x4 NEG8 = {-8.f, -8.f, -8.f, -8.f};

  bf16x8 aq[2];
#pragma unroll
  for (int kk = 0; kk < 2; ++kk)
    aq[kk] = *(const bf16x8*)(Qp + (size_t)(q0 + c)*DK_ + kk*32 + hg*8);

  f32x4 oacc[4], lacc;
#pragma unroll
  for (int n = 0; n < 4; ++n) oacc[n] = (f32x4){0.f, 0.f, 0.f, 0.f};
  lacc = (f32x4){0.f, 0.f, 0.f, 0.f};

  const int nkv = qt + 1;

#define STAGE(T, BI)                                                          \
  do {                                                                        \
    const int kv0s = (T) * 64;                                                \
    _Pragma("unroll")                                                         \
    for (int i = 0; i < 2; ++i) {                                             \
      gload_lds16(Kp + (size_t)(kv0s + i*32 + srow)*DK_ + schunk*8,           \
                  &Kb[BI][(i*32 + w*8)*64]);                                  \
      gload_lds16(Vp + (size_t)(i*32 + srow)*S_ + kv0s + schunk*8,            \
                  &Vb[BI][(i*32 + w*8)*64]);                                  \
    }                                                                         \
  } while (0)

  STAGE(0, 0);

  for (int t = 0; t < nkv; ++t) {
    const int bi = t & 1;
    asm volatile("s_waitcnt vmcnt(0)" ::: "memory");
    __builtin_amdgcn_s_barrier();
    asm volatile("" ::: "memory");
    if (t + 1 < nkv) STAGE(t + 1, bi ^ 1);   // in flight under compute

    const int kv0 = t * 64;

    bf16x8 bk[4][2];
#pragma unroll
    for (int n = 0; n < 4; ++n)
#pragma unroll
      for (int kk = 0; kk < 2; ++kk)
        bk[n][kk] = *(const bf16x8*)&Kb[bi][(n*16 + c)*64 + (((kk*4 + hg) ^ (c & 7))*8)];

    // swapped QK^T with C-init = -8: sc4 = K·Q - 8 (static shift folded in)
    f32x4 sc4[4];
    __builtin_amdgcn_s_setprio(1);
#pragma unroll
    for (int n = 0; n < 4; ++n) {
      sc4[n] = __builtin_amdgcn_mfma_f32_16x16x32_bf16(bk[n][0], aq[0], NEG8, 0, 0, 0);
      sc4[n] = __builtin_amdgcn_mfma_f32_16x16x32_bf16(bk[n][1], aq[1], sc4[n], 0, 0, 0);
    }
    __builtin_amdgcn_s_setprio(0);

    bf16x8 bv[4][2];
#pragma unroll
    for (int n = 0; n < 4; ++n)
#pragma unroll
      for (int kk = 0; kk < 2; ++kk)
        bv[n][kk] = *(const bf16x8*)&Vb[bi][(n*16 + c)*64 + (((kk*4 + hg) ^ (c & 7))*8)];

    // causal mask on the diagonal step only
    if (t == qt) {
      const int qg = q0 + c;
#pragma unroll
      for (int n = 0; n < 4; ++n)
#pragma unroll
        for (int r = 0; r < 4; ++r)
          if (kv0 + n*16 + hg*4 + r > qg) sc4[n][r] = -INFINITY;
    }

    // exp2 (raw v_exp_f32) + packed bf16 -> Ps (stride 64, XOR chunk swizzle:
    // write chunk (n*2+(hg>>1))^(c&7), sub-offset (hg&1)*4)
#pragma unroll
    for (int n = 0; n < 4; ++n) {
      union { __hip_bfloat162 h2[2]; ushort4 u; } pk;
      pk.h2[0] = __float22bfloat162_rn(make_float2(
          __builtin_amdgcn_exp2f(sc4[n][0]),
          __builtin_amdgcn_exp2f(sc4[n][1])));
      pk.h2[1] = __float22bfloat162_rn(make_float2(
          __builtin_amdgcn_exp2f(sc4[n][2]),
          __builtin_amdgcn_exp2f(sc4[n][3])));
      *(ushort4*)&Ps[w][c*64 + (((n*2 + (hg>>1)) ^ (c & 7))*8) + (hg&1)*4] = pk.u;
    }

    // PV: oacc[q][d] += P[q][kv] * V^T[d][kv]; l[q] += P[q][kv]*1
    bf16x8 ap[2];
#pragma unroll
    for (int kk = 0; kk < 2; ++kk)
      ap[kk] = *(const bf16x8*)&Ps[w][c*64 + (((kk*4 + hg) ^ (c & 7))*8)];
    __builtin_amdgcn_s_setprio(1);
#pragma unroll
    for (int n = 0; n < 4; ++n)
#pragma unroll
      for (int kk = 0; kk < 2; ++kk)
        oacc[n] = __builtin_amdgcn_mfma_f32_16x16x32_bf16(ap[kk], bv[n][kk], oacc[n], 0, 0, 0);
#pragma unroll
    for (int kk = 0; kk < 2; ++kk)
      lacc = __builtin_amdgcn_mfma_f32_16x16x32_bf16(ap[kk], vones, lacc, 0, 0, 0);
    __builtin_amdgcn_s_setprio(0);

    asm volatile("" ::: "memory");
  }
#undef STAGE

  const int b = head >> 4, h = head & 15;
  float rl[4];
#pragma unroll
  for (int r = 0; r < 4; ++r) rl[r] = 1.0f / lacc[r];
#pragma unroll
  for (int n = 0; n < 4; ++n)
#pragma unroll
    for (int r = 0; r < 4; ++r) {
      const int s = q0 + hg*4 + r;
      const int d = n*16 + c;
      Og[((size_t)b*S_ + s)*D_ + h*DK_ + d] = f2bf(oacc[n][r] * rl[r]);
    }
}

// ---------------- launcher ----------------
extern "C" void kernel_launch(void* const* d_in, const int* in_sizes, int n_in,
                              void* d_out, int out_size, void* d_ws, size_t ws_size,
                              hipStream_t stream) {
  const float* x = (const float*)d_in[0];
  const float* Wm[4] = {(const float*)d_in[1], (const float*)d_in[2],
                        (const float*)d_in[3], (const float*)d_in[4]};
  const int* tp = (const int*)d_in[5];
  float* out = (float*)d_out;

  unsigned short* ws = (unsigned short*)d_ws;
  const size_t MD = (size_t)M_ * D_;                 // 4M elements
  unsigned short* xb  = ws;                          // x bf16; reused as attn buffer
  unsigned short* wb  = ws + MD;                     // 4 weight mats bf16
  unsigned short* qws = ws + MD + 4*(size_t)D_*K_;   // Q,K (row-major), V^T
  float2* tab = (float2*)(ws + MD + 4*(size_t)D_*K_ + 3*MD);  // [S][32]

  k_cvt<<<dim3(8448), 256, 0, stream>>>(x, Wm[0], Wm[1], Wm[2], Wm[3], xb, wb, tp, tab);

  k_gemm0<<<dim3(M_/128, 16), 512, 0, stream>>>(xb, wb, qws, tab);

  unsigned short* attn = xb;   // x no longer needed
  k_attn<<<dim3(1024), 256, 0, stream>>>(qws, qws + MD, qws + 2*MD, attn);

  k_gemm1<<<dim3(M_/64, D_/128), 512, 0, stream>>>(attn, wb + 3*(size_t)D_*K_, out);
}

// Round 21
// 86.879 us; speedup vs baseline: 1.1494x; 1.1494x over previous
//
#include <hip/hip_runtime.h>
#include <hip/hip_bf16.h>

#define B_ 2
#define S_ 2048
#define D_ 1024
#define H_ 16
#define DK_ 64
#define M_ (B_*S_)   // 4096 rows
#define K_ D_        // 1024 reduction dim

typedef __attribute__((ext_vector_type(8))) short bf16x8;
typedef __attribute__((ext_vector_type(4))) float f32x4;

__device__ __forceinline__ unsigned short f2bf(float f) {
  unsigned u = __float_as_uint(f);
  u += 0x7fff + ((u >> 16) & 1);   // round-to-nearest-even
  return (unsigned short)(u >> 16);
}

// async global->LDS, 16B per lane. LDS base wave-uniform; HW writes base+lane*16.
__device__ __forceinline__ void gload_lds16(const void* g, void* l) {
  __builtin_amdgcn_global_load_lds(
      (const __attribute__((address_space(1))) unsigned int*)(unsigned long long)g,
      (__attribute__((address_space(3))) unsigned int*)(unsigned int)(unsigned long long)l,
      16, 0, 0);
}

// ---------------- unified fp32->bf16 convert + RoPE table, one launch ------
__global__ __launch_bounds__(256) void k_cvt(
    const float* __restrict__ x,
    const float* __restrict__ w0, const float* __restrict__ w1,
    const float* __restrict__ w2, const float* __restrict__ w3,
    unsigned short* __restrict__ xb, unsigned short* __restrict__ wb,
    const int* __restrict__ pos, float2* __restrict__ tab) {
  const int bid = blockIdx.x;
  if (bid >= 8192) {
    int t = (bid - 8192) * 256 + threadIdx.x;   // S*32
    int s = t >> 5, j = t & 31;
    float inv = powf(10000.0f, -(float)j / 32.0f);
    float ang = (float)pos[s] * inv;
    tab[t] = make_float2(cosf(ang), sinf(ang));
    return;
  }
  const float* sp;
  unsigned short* dp;
  size_t off;
  if (bid < 4096) {
    sp = x; dp = xb; off = (size_t)bid * 1024 + threadIdx.x * 4;
  } else {
    const int wi = (bid - 4096) >> 10;
    sp = (wi == 0) ? w0 : (wi == 1) ? w1 : (wi == 2) ? w2 : w3;
    dp = wb + (size_t)wi * D_ * K_;
    off = (size_t)((bid - 4096) & 1023) * 1024 + threadIdx.x * 4;
  }
  float4 v = *(const float4*)(sp + off);
  ushort4 o;
  o.x = f2bf(v.x); o.y = f2bf(v.y); o.z = f2bf(v.z); o.w = f2bf(v.w);
  *(ushort4*)(dp + off) = o;
}

// ---------------- QKV GEMM: 128x192 tiles, BK=64, 8 WAVES ------------------
__global__ __launch_bounds__(512, 4) void k_gemm0(
    const unsigned short* __restrict__ A,      // [M,K] bf16 (x)
    const unsigned short* __restrict__ Wall,   // concat (Wq;Wk;Wv) [3072,1024]
    unsigned short* __restrict__ qkv,          // [z][B*H][...] outputs
    const float2* __restrict__ tab)
{
  __shared__ unsigned short SA[2][128*64];     // 32KB
  __shared__ unsigned short SB[2][192*64];     // 48KB
  const int tid = threadIdx.x, lane = tid & 63, w = tid >> 6;   // w 0..7
  const int wr = w >> 2, wc = w & 3;           // 2x4 wave grid
  const int c = lane & 15, hg = lane >> 4;
  const int m0 = blockIdx.x * 128;
  const int n0 = blockIdx.y * 192;             // in concat col space [0,3072)
  const unsigned short* Ag = A + (size_t)m0 * K_;
  const unsigned short* Bg = Wall + (size_t)n0 * K_;

  f32x4 acc[4][3];
#pragma unroll
  for (int m = 0; m < 4; ++m)
#pragma unroll
    for (int n = 0; n < 3; ++n) acc[m][n] = (f32x4){0.f, 0.f, 0.f, 0.f};

  const int srow   = w*8 + (lane >> 3);        // + i*64 (8 waves x 8 rows/round)
  const int schunk = (lane & 7) ^ (lane >> 3); // source chunk XOR row&7

#define GS0(KT, BI)                                                           \
  do {                                                                        \
    _Pragma("unroll")                                                         \
    for (int i = 0; i < 2; ++i)                                               \
      gload_lds16(Ag + (size_t)(i*64 + srow)*K_ + (KT) + schunk*8,            \
                  &SA[BI][(i*64 + w*8)*64]);                                  \
    _Pragma("unroll")                                                         \
    for (int i = 0; i < 3; ++i)                                               \
      gload_lds16(Bg + (size_t)(i*64 + srow)*K_ + (KT) + schunk*8,            \
                  &SB[BI][(i*64 + w*8)*64]);                                  \
  } while (0)

  GS0(0, 0);
  for (int t = 0; t < K_/64; ++t) {
    asm volatile("s_waitcnt vmcnt(0)" ::: "memory");
    __builtin_amdgcn_s_barrier();
    asm volatile("" ::: "memory");
    if (t + 1 < K_/64) GS0((t+1)*64, (t & 1) ^ 1);

    const int bi = t & 1;
#pragma unroll
    for (int kk = 0; kk < 2; ++kk) {
      bf16x8 af[4], bfr[3];
#pragma unroll
      for (int m = 0; m < 4; ++m)
        af[m] = *(const bf16x8*)&SA[bi][(wr*64 + m*16 + c)*64 + (((kk*4 + hg) ^ (c & 7))*8)];
#pragma unroll
      for (int n = 0; n < 3; ++n)
        bfr[n] = *(const bf16x8*)&SB[bi][(wc*48 + n*16 + c)*64 + (((kk*4 + hg) ^ (c & 7))*8)];
#pragma unroll
      for (int m = 0; m < 4; ++m)
#pragma unroll
        for (int n = 0; n < 3; ++n)
          acc[m][n] = __builtin_amdgcn_mfma_f32_16x16x32_bf16(af[m], bfr[n], acc[m][n], 0, 0, 0);
    }
  }
#undef GS0

#pragma unroll
  for (int m = 0; m < 4; ++m)
#pragma unroll
    for (int n = 0; n < 3; ++n) {
      const int row0 = m0 + wr*64 + m*16 + hg*4;
      const int col  = n0 + wc*48 + n*16 + c;
      const int z = col >> 10;
      const int colz = col & 1023;
      const int h = colz >> 6, d = colz & 63;
      unsigned short* dst = qkv + (size_t)z * M_ * D_;
      if (z == 2) {
        // V^T: [B*H][DK][S], 4 consecutive s per lane (8B store)
        const int b = row0 >> 11, s0 = row0 & (S_ - 1);
        ushort4 o;
        o.x = f2bf(acc[m][n][0]); o.y = f2bf(acc[m][n][1]);
        o.z = f2bf(acc[m][n][2]); o.w = f2bf(acc[m][n][3]);
        *(ushort4*)&dst[((size_t)(b*H_ + h)*DK_ + d)*S_ + s0] = o;
      } else {
        const float post = (z == 0) ? 0.18033688f : 1.0f;   // 0.125*log2(e)
        const float sgn = (d & 1) ? 1.0f : -1.0f;
#pragma unroll
        for (int r = 0; r < 4; ++r) {
          const int row = row0 + r;
          const int b = row >> 11, s = row & (S_ - 1);
          float v  = acc[m][n][r];
          float pv = __shfl_xor(v, 1);          // pair partner: d^1 == lane^1
          float2 cs = tab[s*32 + (d >> 1)];
          float ov = (v * cs.x + sgn * pv * cs.y) * post;
          dst[((size_t)(b*H_ + h)*S_ + s)*DK_ + d] = f2bf(ov);
        }
      }
    }
}

// ---------------- output GEMM: attn @ Wo^T, 64x128 tiles, 8 WAVES ----------
__global__ __launch_bounds__(512, 4) void k_gemm1(
    const unsigned short* __restrict__ A,      // [M,K] bf16 (attn)
    const unsigned short* __restrict__ Wo,     // [D,K] bf16
    float* __restrict__ fout)                  // [M,D] fp32 (d_out)
{
  __shared__ unsigned short As[2][64*64];      // 16KB
  __shared__ unsigned short Bs[2][128*64];     // 32KB
  const int tid = threadIdx.x, lane = tid & 63, w = tid >> 6;   // w 0..7
  const int wr = w >> 2, wc = w & 3;           // 2x4 wave grid; wave-tile 32x32
  const int c = lane & 15, hg = lane >> 4;
  const int m0 = blockIdx.x * 64, n0 = blockIdx.y * 128;
  const unsigned short* Ag = A + (size_t)m0 * K_;
  const unsigned short* Bg = Wo + (size_t)n0 * K_;

  f32x4 acc[2][2];
#pragma unroll
  for (int m = 0; m < 2; ++m)
#pragma unroll
    for (int n = 0; n < 2; ++n) acc[m][n] = (f32x4){0.f, 0.f, 0.f, 0.f};

  const int srow   = w*8 + (lane >> 3);
  const int schunk = (lane & 7) ^ (lane >> 3);

#define GS1(KT, BI)                                                           \
  do {                                                                        \
    gload_lds16(Ag + (size_t)srow*K_ + (KT) + schunk*8,                       \
                &As[BI][(w*8)*64]);                                           \
    _Pragma("unroll")                                                         \
    for (int i = 0; i < 2; ++i)                                               \
      gload_lds16(Bg + (size_t)(i*64 + srow)*K_ + (KT) + schunk*8,            \
                  &Bs[BI][(i*64 + w*8)*64]);                                  \
  } while (0)

  GS1(0, 0);
  for (int t = 0; t < K_/64; ++t) {
    asm volatile("s_waitcnt vmcnt(0)" ::: "memory");
    __builtin_amdgcn_s_barrier();
    asm volatile("" ::: "memory");
    if (t + 1 < K_/64) GS1((t+1)*64, (t & 1) ^ 1);

    const int bi = t & 1;
#pragma unroll
    for (int kk = 0; kk < 2; ++kk) {
      bf16x8 af[2], bfr[2];
#pragma unroll
      for (int m = 0; m < 2; ++m)
        af[m] = *(const bf16x8*)&As[bi][(wr*32 + m*16 + c)*64 + (((kk*4 + hg) ^ (c & 7))*8)];
#pragma unroll
      for (int n = 0; n < 2; ++n)
        bfr[n] = *(const bf16x8*)&Bs[bi][(wc*32 + n*16 + c)*64 + (((kk*4 + hg) ^ (c & 7))*8)];
#pragma unroll
      for (int m = 0; m < 2; ++m)
#pragma unroll
        for (int n = 0; n < 2; ++n)
          acc[m][n] = __builtin_amdgcn_mfma_f32_16x16x32_bf16(af[m], bfr[n], acc[m][n], 0, 0, 0);
    }
  }
#undef GS1

#pragma unroll
  for (int m = 0; m < 2; ++m)
#pragma unroll
    for (int n = 0; n < 2; ++n) {
      const int row0 = m0 + wr*32 + m*16 + hg*4;
      const int col  = n0 + wc*32 + n*16 + c;
#pragma unroll
      for (int r = 0; r < 4; ++r)
        fout[(size_t)(row0 + r)*D_ + col] = acc[m][n][r];
    }
}

// ---------------- causal flash attention: 1024 single-tile blocks ----------
// r18 configuration restored (best measured: 87.47us total). One 64-row
// q-tile per block, LDS 41.25KB -> 3 blocks/CU, grid 1024 > capacity 768 ->
// hardware refill load-balances, heavy-first (LPT). bv after QK^T.
__global__ __launch_bounds__(256) void k_attn(
    const unsigned short* __restrict__ Qg,   // [B*H][S][DK]
    const unsigned short* __restrict__ Kg,   // [B*H][S][DK]
    const unsigned short* __restrict__ Vtg,  // [B*H][DK][S]
    unsigned short* __restrict__ Og)         // [B][S][D]
{
  __shared__ unsigned short Kb[2][64*64];    // 16KB
  __shared__ unsigned short Vb[2][64*64];    // 16KB
  __shared__ unsigned short Ps[4][16*72];    // 9KB (per-wave P tile, 16 rows)

  const int tid = threadIdx.x, lane = tid & 63, w = tid >> 6;
  const int bid = blockIdx.x;                // 0..1023
  const int xcd = bid & 7, sub = (bid >> 3) & 3;
  const int head = xcd * 4 + sub;            // 4 heads per XCD (KV L2-resident)
  const int qt = 31 - (bid >> 5);            // heavy-first (LPT with refill)
  const int q0 = qt * 64 + w * 16;           // this wave's first q row
  const int c = lane & 15, hg = lane >> 4;

  const unsigned short* Qp = Qg + (size_t)head * S_ * DK_;
  const unsigned short* Kp = Kg + (size_t)head * S_ * DK_;
  const unsigned short* Vp = Vtg + (size_t)head * DK_ * S_;

  const int srow   = w*8 + (lane >> 3);
  const int schunk = (lane & 7) ^ (lane >> 3);

  const short ONE_BF = (short)0x3F80;
  const bf16x8 vones = {ONE_BF, ONE_BF, ONE_BF, ONE_BF, ONE_BF, ONE_BF, ONE_BF, ONE_BF};
  const f32x4 NEG8 = {-8.f, -8.f, -8.f, -8.f};

  bf16x8 aq[2];
#pragma unroll
  for (int kk = 0; kk < 2; ++kk)
    aq[kk] = *(const bf16x8*)(Qp + (size_t)(q0 + c)*DK_ + kk*32 + hg*8);

  f32x4 oacc[4], lacc;
#pragma unroll
  for (int n = 0; n < 4; ++n) oacc[n] = (f32x4){0.f, 0.f, 0.f, 0.f};
  lacc = (f32x4){0.f, 0.f, 0.f, 0.f};

  const int nkv = qt + 1;

#define STAGE(T, BI)                                                          \
  do {                                                                        \
    const int kv0s = (T) * 64;                                                \
    _Pragma("unroll")                                                         \
    for (int i = 0; i < 2; ++i) {                                             \
      gload_lds16(Kp + (size_t)(kv0s + i*32 + srow)*DK_ + schunk*8,           \
                  &Kb[BI][(i*32 + w*8)*64]);                                  \
      gload_lds16(Vp + (size_t)(i*32 + srow)*S_ + kv0s + schunk*8,            \
                  &Vb[BI][(i*32 + w*8)*64]);                                  \
    }                                                                         \
  } while (0)

  STAGE(0, 0);

  for (int t = 0; t < nkv; ++t) {
    const int bi = t & 1;
    asm volatile("s_waitcnt vmcnt(0)" ::: "memory");
    __builtin_amdgcn_s_barrier();
    asm volatile("" ::: "memory");
    if (t + 1 < nkv) STAGE(t + 1, bi ^ 1);   // in flight under compute

    const int kv0 = t * 64;

    bf16x8 bk[4][2];
#pragma unroll
    for (int n = 0; n < 4; ++n)
#pragma unroll
      for (int kk = 0; kk < 2; ++kk)
        bk[n][kk] = *(const bf16x8*)&Kb[bi][(n*16 + c)*64 + (((kk*4 + hg) ^ (c & 7))*8)];

    // swapped QK^T with C-init = -8: sc4 = K·Q - 8 (static shift folded in)
    f32x4 sc4[4];
    __builtin_amdgcn_s_setprio(1);
#pragma unroll
    for (int n = 0; n < 4; ++n) {
      sc4[n] = __builtin_amdgcn_mfma_f32_16x16x32_bf16(bk[n][0], aq[0], NEG8, 0, 0, 0);
      sc4[n] = __builtin_amdgcn_mfma_f32_16x16x32_bf16(bk[n][1], aq[1], sc4[n], 0, 0, 0);
    }
    __builtin_amdgcn_s_setprio(0);

    bf16x8 bv[4][2];
#pragma unroll
    for (int n = 0; n < 4; ++n)
#pragma unroll
      for (int kk = 0; kk < 2; ++kk)
        bv[n][kk] = *(const bf16x8*)&Vb[bi][(n*16 + c)*64 + (((kk*4 + hg) ^ (c & 7))*8)];

    // causal mask on the diagonal step only
    if (t == qt) {
      const int qg = q0 + c;
#pragma unroll
      for (int n = 0; n < 4; ++n)
#pragma unroll
        for (int r = 0; r < 4; ++r)
          if (kv0 + n*16 + hg*4 + r > qg) sc4[n][r] = -INFINITY;
    }

    // exp2 (raw v_exp_f32) + native packed bf16 conversion -> P rows q=c
#pragma unroll
    for (int n = 0; n < 4; ++n) {
      union { __hip_bfloat162 h2[2]; ushort4 u; } pk;
      pk.h2[0] = __float22bfloat162_rn(make_float2(
          __builtin_amdgcn_exp2f(sc4[n][0]),
          __builtin_amdgcn_exp2f(sc4[n][1])));
      pk.h2[1] = __float22bfloat162_rn(make_float2(
          __builtin_amdgcn_exp2f(sc4[n][2]),
          __builtin_amdgcn_exp2f(sc4[n][3])));
      *(ushort4*)&Ps[w][c*72 + n*16 + hg*4] = pk.u;
    }

    // PV: oacc[q][d] += P[q][kv] * V^T[d][kv]; l[q] += P[q][kv]*1
    bf16x8 ap[2];
#pragma unroll
    for (int kk = 0; kk < 2; ++kk)
      ap[kk] = *(const bf16x8*)&Ps[w][c*72 + kk*32 + hg*8];
    __builtin_amdgcn_s_setprio(1);
#pragma unroll
    for (int n = 0; n < 4; ++n)
#pragma unroll
      for (int kk = 0; kk < 2; ++kk)
        oacc[n] = __builtin_amdgcn_mfma_f32_16x16x32_bf16(ap[kk], bv[n][kk], oacc[n], 0, 0, 0);
#pragma unroll
    for (int kk = 0; kk < 2; ++kk)
      lacc = __builtin_amdgcn_mfma_f32_16x16x32_bf16(ap[kk], vones, lacc, 0, 0, 0);
    __builtin_amdgcn_s_setprio(0);

    asm volatile("" ::: "memory");
  }
#undef STAGE

  const int b = head >> 4, h = head & 15;
  float rl[4];
#pragma unroll
  for (int r = 0; r < 4; ++r) rl[r] = 1.0f / lacc[r];
#pragma unroll
  for (int n = 0; n < 4; ++n)
#pragma unroll
    for (int r = 0; r < 4; ++r) {
      const int s = q0 + hg*4 + r;
      const int d = n*16 + c;
      Og[((size_t)b*S_ + s)*D_ + h*DK_ + d] = f2bf(oacc[n][r] * rl[r]);
    }
}

// ---------------- launcher ----------------
extern "C" void kernel_launch(void* const* d_in, const int* in_sizes, int n_in,
                              void* d_out, int out_size, void* d_ws, size_t ws_size,
                              hipStream_t stream) {
  const float* x = (const float*)d_in[0];
  const float* Wm[4] = {(const float*)d_in[1], (const float*)d_in[2],
                        (const float*)d_in[3], (const float*)d_in[4]};
  const int* tp = (const int*)d_in[5];
  float* out = (float*)d_out;

  unsigned short* ws = (unsigned short*)d_ws;
  const size_t MD = (size_t)M_ * D_;                 // 4M elements
  unsigned short* xb  = ws;                          // x bf16; reused as attn buffer
  unsigned short* wb  = ws + MD;                     // 4 weight mats bf16
  unsigned short* qws = ws + MD + 4*(size_t)D_*K_;   // Q,K (row-major), V^T
  float2* tab = (float2*)(ws + MD + 4*(size_t)D_*K_ + 3*MD);  // [S][32]

  k_cvt<<<dim3(8448), 256, 0, stream>>>(x, Wm[0], Wm[1], Wm[2], Wm[3], xb, wb, tp, tab);

  k_gemm0<<<dim3(M_/128, 16), 512, 0, stream>>>(xb, wb, qws, tab);

  unsigned short* attn = xb;   // x no longer needed
  k_attn<<<dim3(1024), 256, 0, stream>>>(qws, qws + MD, qws + 2*MD, attn);

  k_gemm1<<<dim3(M_/64, D_/128), 512, 0, stream>>>(attn, wb + 3*(size_t)D_*K_, out);
}